// Round 5
// baseline (144.277 us; speedup 1.0000x reference)
//
#include <hip/hip_runtime.h>
#include <math.h>

// Problem constants
constexpr int Bn = 32;
constexpr int Cn = 512;
constexpr int Tn = 1024;
constexpr int KS = 13;

// Tiling
constexpr int CB   = 32;           // channels per block -> 512 blocks, 2 blocks/CU
constexpr int TT   = 128;          // timesteps per chunk (halves period count vs r9)
constexpr int NCH  = Tn / TT;      // 8 chunks
constexpr int DSTR = TT + 2;       // 130: row=520B, 8B-aligned; banks (2c+2q)%32 -> 2-way = free
                                   // (r12 FAILURE: DSTR was left at 66 from the TT=64 design;
                                   //  conv writes reach float offset 127 -> rows overflowed into
                                   //  each other and past the array. Row stride must be >= TT.)
constexpr int NCW  = 4;            // conv waves
constexpr int SEG  = CB / NCW;     // 8 output rows per conv thread
constexpr int NL   = SEG + KS - 1; // 20 input rows per conv thread (float2 each)

// ---------------------------------------------------------------------------
// r14 = r13 resubmitted verbatim (round-4 bench was an infra failure: the
// MI355X container died twice before running; no measurement was taken).
// Rationale (unchanged): r8/r9/r10 all show ~6.5-7K cyc per barrier period vs
// ~1-1.5K cyc of laggard-stage work, and VALUBusy barely moves with 2x waves
// -> the stall is a fixed per-period convoy cost (barrier round + latency
// warmups), shared by all co-resident waves. Attack: halve the period count.
//  (1) TT 64->128: 8 periods. Register ring shrinks to 2 float2[20] buffers
//      (distance-1 prefetch spans a full period >> HBM latency). All global
//      I/O becomes dwordx2 (lane owns t=2L,2L+1): half the VMEM instrs.
//  (2) scan compare-reuse: spike predicate of step j IS the reset predicate
//      of step j+1 -> 7 VALU/step (was 9), identical rounded-op sequence.
//  (3) spike bits as uint4/channel/chunk; scan publishes via 1 ds_write_b128.
// Structure otherwise = r9 (best measured): CB=32, register-ring conv,
// role-split waves, raw s_barrier dbuf, no vmcnt drains anywhere.
// Liveness (10 barriers B0..B9): conv(K) in (B(K-1),B(K)) -> D[K&1];
// scan(k) in (B(k),B(k+1)) reads D[k&1], writes Sb[k&1]; store(k) in
// (B(k+1),B(k+2)) reads Sb[k&1]. All rewrites disjoint from reads.
// Math (kw double-exp emulation, ascending no-FMA conv, scan op order) is
// bit-identical to the validated r2..r9 kernels.
// ---------------------------------------------------------------------------

__device__ __forceinline__ void wg_barrier() {
  asm volatile("" ::: "memory");
  __builtin_amdgcn_s_barrier();
  asm volatile("" ::: "memory");
}
__device__ __forceinline__ void lds_fence() {
  asm volatile("s_waitcnt lgkmcnt(0)" ::: "memory");
}

// one scan step: reset uses PREVIOUS step's spike predicate (spkf), identical
// to computing (mem_old > 0.5 ? 0.5 : 0) -- one cmp per step instead of two.
#define SSTEP(DV, BP, W)                                                 \
  {                                                                      \
    const float rthr = spkf;                                             \
    float a_  = __fmul_rn(0.95f, mem);                                   \
    float s2_ = __fadd_rn(a_, (DV));                                     \
    mem = __fsub_rn(s2_, rthr);                                          \
    const bool sp_ = (mem > 0.5f);                                       \
    spkf = sp_ ? 0.5f : 0.0f;                                            \
    (W) |= sp_ ? (1u << (BP)) : 0u;                                      \
  }

// 16 scan steps from a float2[8] register group; TB is a multiple of 16 and
// (TB..TB+15) lies inside one 32-bit word W (passed explicitly).
#define SCAN16(DV2, TB, W)                                               \
  _Pragma("unroll")                                                      \
  for (int q = 0; q < 8; ++q) {                                          \
    SSTEP(DV2[q].x, (((TB) + 2 * q) & 31), W)                            \
    SSTEP(DV2[q].y, (((TB) + 2 * q + 1) & 31), W)                        \
  }

#define LOADG2(DST, G)                                                   \
  _Pragma("unroll")                                                      \
  for (int q = 0; q < 8; ++q) DST[q] = Dv[8 * (G) + q];

__global__ __launch_bounds__(384, 3)
void snn_fused(const float* __restrict__ x, const float* __restrict__ wp,
               float* __restrict__ out) {
  __shared__ __align__(16) float DA[CB][DSTR];   // drive double buffer
  __shared__ __align__(16) float DB[CB][DSTR];   // (33.3 KB total)
  __shared__ __align__(16) uint4 SbA[CB];        // spike bitmask dbuf (1 KB)
  __shared__ __align__(16) uint4 SbB[CB];

  const int tid = threadIdx.x;
  const int b   = blockIdx.y;
  const int c0  = blockIdx.x * CB;
  const long xbase = (long)b * Cn * Tn;

  if (tid < 64) {
    // ======================= scan wave (lanes >= CB masked) =============
    const int c = tid;
    float mem = 0.0f, spkf = 0.0f;               // carried across all 1024 t
    wg_barrier();                                // B0: D(0) published
    for (int k = 0; k < NCH; ++k) {
      if (c < CB) {
        const float2* Dv =
            (const float2*)((k & 1) ? &DB[c][0] : &DA[c][0]);
        unsigned m0 = 0u, m1 = 0u, m2 = 0u, m3 = 0u;
        float2 ga[8], gb[8];                     // named groups, const idx
        LOADG2(ga, 0)
        LOADG2(gb, 1)                            // lookahead one group
        SCAN16(ga, 0,  m0)  LOADG2(ga, 2)
        SCAN16(gb, 16, m0)  LOADG2(gb, 3)
        SCAN16(ga, 32, m1)  LOADG2(ga, 4)
        SCAN16(gb, 48, m1)  LOADG2(gb, 5)
        SCAN16(ga, 64, m2)  LOADG2(ga, 6)
        SCAN16(gb, 80, m2)  LOADG2(gb, 7)
        SCAN16(ga, 96, m3)
        SCAN16(gb, 112, m3)
        ((k & 1) ? SbB : SbA)[c] = make_uint4(m0, m1, m2, m3);
      }
      lds_fence();                               // reads+Sb write retired
      wg_barrier();                              // B(k+1)
    }
    wg_barrier();                                // B9
  } else if (tid < 64 + 64 * NCW) {
    // ====== conv waves (register-ring producers, loads + LDS writes) ====
    const int ctid = tid - 64;
    const int col  = ctid & 63;                  // lane -> t-cols 2L,2L+1
    const int segS = (ctid >> 6) * SEG;          // 0,8,16,24
    const int cin0 = c0 + segS - 6;

    // ---- Gaussian weights, numpy float32 bit-emulation (validated) ----
    float kw[KS];
    {
      float w  = wp[0];
      float wc = fminf(fmaxf(w, 1.0f), 10.0f);   // clip(w, 1, 10)
      float sigma = __fadd_rn(5.5f, wc);
      float e[KS];
#pragma unroll
      for (int i = 0; i < KS; ++i) {
        float q = __fdiv_rn((float)(i - 6), sigma);
        float t = __fmul_rn(-0.5f, __fmul_rn(q, q));
        e[i] = (float)exp((double)t);
      }
      // numpy pairwise_sum order for n=13
      float s = __fadd_rn(
          __fadd_rn(__fadd_rn(e[0], e[1]), __fadd_rn(e[2], e[3])),
          __fadd_rn(__fadd_rn(e[4], e[5]), __fadd_rn(e[6], e[7])));
      s = __fadd_rn(s, e[8]);  s = __fadd_rn(s, e[9]);  s = __fadd_rn(s, e[10]);
      s = __fadd_rn(s, e[11]); s = __fadd_rn(s, e[12]);
#pragma unroll
      for (int i = 0; i < KS; ++i) kw[i] = __fdiv_rn(e[i], s);
    }

    float2 xA[NL], xB[NL];                       // 2-buffer register ring

    auto load_chunk = [&](int m, float2* dst) {
#pragma unroll
      for (int j = 0; j < NL; ++j) {
        const int gc = cin0 + j;
        float2 v = make_float2(0.0f, 0.0f);
        if (gc >= 0 && gc < Cn)                  // zero pad; per-wave uniform
          v = *(const float2*)&x[xbase + (long)gc * Tn + m * TT + 2 * col];
        dst[j] = v;
      }
    };
    auto conv_chunk = [&](const float2* xs, float (*D)[DSTR]) {
#pragma unroll
      for (int r = 0; r < SEG; ++r) {
        float ax = __fmul_rn(kw[0], xs[r].x);    // ascending, no FMA
        float ay = __fmul_rn(kw[0], xs[r].y);
#pragma unroll
        for (int i = 1; i < KS; ++i) {
          ax = __fadd_rn(ax, __fmul_rn(kw[i], xs[r + i].x));
          ay = __fadd_rn(ay, __fmul_rn(kw[i], xs[r + i].y));
        }
        float2 o = make_float2(__fsub_rn(xs[r + 6].x, ax),
                               __fsub_rn(xs[r + 6].y, ay));
        *(float2*)&D[segS + r][2 * col] = o;     // ds_write_b64, x - x_mean
      }
    };

    // prologue: both ring slots in flight; conv(0) auto-waits vmcnt(20)
    load_chunk(0, xA);
    load_chunk(1, xB);
    conv_chunk(xA, DA);                          // chunk 0 -> DA
    lds_fence();
    wg_barrier();                                // B0

    // STEPC(K): issue loads for chunk K+1 (consumed next period: distance-1
    // across a full period >> HBM latency; the auto vmcnt before the conv's
    // first ring read is ~vmcnt(20), never 0), conv chunk K, barrier.
#define STEPC(K, BL, BC, DD)                                             \
    do {                                                                 \
      if ((K) + 1 < NCH) load_chunk((K) + 1, BL);                        \
      conv_chunk(BC, DD);                                                \
      lds_fence();                                                       \
      wg_barrier();                                                      \
    } while (0)

    STEPC(1, xA, xB, DB);                        // stage 2->xA, conv 1 (xB)
    STEPC(2, xB, xA, DA);
    STEPC(3, xA, xB, DB);
    STEPC(4, xB, xA, DA);
    STEPC(5, xA, xB, DB);
    STEPC(6, xB, xA, DA);
    STEPC(7, xA, xB, DB);                        // K=7: no stage
#undef STEPC
    wg_barrier();                                // B8
    wg_barrier();                                // B9
  } else {
    // ====== store wave (LDS reads + global stores, NEVER waits vmcnt) ===
    const int col = tid & 63;                    // lane -> t-cols 2L,2L+1
    const bool sel1 = (col & 16) != 0;           // word-pair select
    const bool sel2 = (col & 32) != 0;
    const unsigned sh = (unsigned)(col & 15) * 2u;
    wg_barrier();                                // B0
    wg_barrier();                                // B1
    for (int k = 0; k < NCH; ++k) {
      const uint4* Sp = (k & 1) ? SbB : SbA;
      const long obase = xbase + (long)c0 * Tn + (long)k * TT + 2 * col;
#pragma unroll
      for (int r = 0; r < CB; ++r) {
        const uint4 q = Sp[r];                   // ds_read_b128 broadcast
        const unsigned w01 = sel1 ? q.y : q.x;
        const unsigned w23 = sel1 ? q.w : q.z;
        const unsigned ws  = sel2 ? w23 : w01;
        const unsigned bb  = ws >> sh;
        float2 o;
        o.x = (bb & 1u) ? 1.0f : 0.0f;
        o.y = (bb & 2u) ? 1.0f : 0.0f;
        *(float2*)&out[obase + (long)r * Tn] = o; // fire & forget dwordx2
      }
      wg_barrier();                              // B(k+2)
    }
  }
}

extern "C" void kernel_launch(void* const* d_in, const int* in_sizes, int n_in,
                              void* d_out, int out_size, void* d_ws, size_t ws_size,
                              hipStream_t stream) {
  const float* x  = (const float*)d_in[0];
  const float* w  = (const float*)d_in[1];
  float* out      = (float*)d_out;
  dim3 grid(Cn / CB, Bn, 1);
  snn_fused<<<grid, 384, 0, stream>>>(x, w, out);
}

// Round 6
// 133.132 us; speedup vs baseline: 1.0837x; 1.0837x over previous
//
#include <hip/hip_runtime.h>
#include <math.h>

// Problem constants
constexpr int Bn = 32;
constexpr int Cn = 512;
constexpr int Tn = 1024;
constexpr int KS = 13;

// Wave-pipeline tiling
constexpr int WC   = 16;            // channels owned per wave
constexpr int TT   = 64;            // timesteps per chunk
constexpr int NCH  = Tn / TT;       // 16 chunks
constexpr int NR   = WC + KS - 1;   // 28 x-rows loaded per chunk
constexpr int DSTR = 68;            // Dw row stride: 272B rows, 16B-aligned (float4 reads);
                                    // banks (68c+t)%32 = (4c+t)%32 -> worst 2-way = free
constexpr int WPB  = 4;             // waves per block (1 block/CU, 1 wave/SIMD)

// ---------------------------------------------------------------------------
// r15: structural rewrite -- self-contained wave pipelines, ZERO barriers.
// Evidence: every role-split variant (r8 spin 46.8us, r9 barrier 43.4, r10
// 4blk/CU 55.2, r14 fat-period 64.5) pays ~5K cyc/period convoy overhead:
// the barrier locksteps 6 waves so any wave's stall is everyone's stall.
// r14 post-mortem: fat periods also blow the VGPR budget (ring spilled,
// VGPR_Count=84 < 120 needed -> scratch, period cost 3x). Fix: remove the
// handoff entirely. Each wave owns (batch b, 16 channels) end-to-end:
//   per chunk k: load 28 x-rows (lane=t, coalesced dwordx1)
//                conv in regs -> private LDS transpose slice (lane=t)
//                scan (lane=channel, 16 active) from LDS float4 groups
//                store spikes (lane=t, fire & forget)
// Cross-phase ordering is wave-internal lgkmcnt (in-order DS pipe) --
// compiler-managed; NO s_barrier, NO inter-wave LDS, NO flags anywhere.
// Scan(k)'s serial dep chain (~900cyc) overlaps conv(k+1)'s independent
// instrs in the same basic block. x-loads are issued one full chunk ahead
// (distance-2 buffer rotation, ~2K cyc cover >> HBM latency).
// 1024 waves = 256 blocks x 4 waves; 1 block/CU. Occupancy reads ~12.5% by
// design -- duration is set by per-wave issue count, not wave count.
// Math (kw double-exp emulation, ascending no-FMA conv, compare-reuse scan)
// is bit-identical to the validated r9/r10/r14 kernels (all absmax 0.0).
// ---------------------------------------------------------------------------

// one scan step: reset uses PREVIOUS step's spike predicate (spkf), identical
// to computing (mem_old > 0.5 ? 0.5 : 0) -- validated in r14 (absmax 0.0).
#define SSTEP(DV, BP, W)                                                 \
  {                                                                      \
    const float rthr = spkf;                                             \
    float a_  = __fmul_rn(0.95f, mem);                                   \
    float s2_ = __fadd_rn(a_, (DV));                                     \
    mem = __fsub_rn(s2_, rthr);                                          \
    const bool sp_ = (mem > 0.5f);                                       \
    spkf = sp_ ? 0.5f : 0.0f;                                            \
    (W) |= sp_ ? (1u << (BP)) : 0u;                                      \
  }

// 16 scan steps from a 16-float register group into word W
#define SCAN16(DV, TB, W)                                                \
  _Pragma("unroll")                                                      \
  for (int j = 0; j < 16; ++j) {                                         \
    SSTEP(DV[j], (((TB) + j) & 31), W)                                   \
  }

// unpack one group of 4 float4s from Dv into a 16-float register array
#define LOADG(DV, G)                                                     \
  { float4 t0_ = Dv[4*(G)+0], t1_ = Dv[4*(G)+1],                         \
           t2_ = Dv[4*(G)+2], t3_ = Dv[4*(G)+3];                         \
    DV[0]=t0_.x;  DV[1]=t0_.y;  DV[2]=t0_.z;  DV[3]=t0_.w;               \
    DV[4]=t1_.x;  DV[5]=t1_.y;  DV[6]=t1_.z;  DV[7]=t1_.w;               \
    DV[8]=t2_.x;  DV[9]=t2_.y;  DV[10]=t2_.z; DV[11]=t2_.w;              \
    DV[12]=t3_.x; DV[13]=t3_.y; DV[14]=t3_.z; DV[15]=t3_.w; }

__global__ __launch_bounds__(256, 1)
void snn_fused(const float* __restrict__ x, const float* __restrict__ wp,
               float* __restrict__ out) {
  // per-wave private LDS: transpose dbuf + spike words (no cross-wave use)
  __shared__ __align__(16) float    Dw[WPB][2][WC][DSTR];  // 34.8 KB
  __shared__            unsigned    Sw[WPB][WC][2];        // 0.5 KB

  const int tid  = threadIdx.x;
  const int w    = tid >> 6;                  // wave in block (0..3)
  const int lane = tid & 63;
  const int wid  = blockIdx.x * WPB + w;      // 0..1023
  const int b    = wid >> 5;                  // batch (0..31)
  const int c0w  = (wid & 31) * WC;           // first owned channel
  const long xbase = (long)b * Cn * Tn;

  // ---- Gaussian weights, numpy float32 bit-emulation (validated) ----
  float kw[KS];
  {
    float wv = wp[0];
    float wc = fminf(fmaxf(wv, 1.0f), 10.0f);     // clip(w, 1, 10)
    float sigma = __fadd_rn(5.5f, wc);
    float e[KS];
#pragma unroll
    for (int i = 0; i < KS; ++i) {
      float q = __fdiv_rn((float)(i - 6), sigma);
      float t = __fmul_rn(-0.5f, __fmul_rn(q, q));
      e[i] = (float)exp((double)t);
    }
    // numpy pairwise_sum order for n=13
    float s = __fadd_rn(
        __fadd_rn(__fadd_rn(e[0], e[1]), __fadd_rn(e[2], e[3])),
        __fadd_rn(__fadd_rn(e[4], e[5]), __fadd_rn(e[6], e[7])));
    s = __fadd_rn(s, e[8]);  s = __fadd_rn(s, e[9]);  s = __fadd_rn(s, e[10]);
    s = __fadd_rn(s, e[11]); s = __fadd_rn(s, e[12]);
#pragma unroll
    for (int i = 0; i < KS; ++i) kw[i] = __fdiv_rn(e[i], s);
  }

  float (*D0)[DSTR] = Dw[w][0];
  float (*D1)[DSTR] = Dw[w][1];
  unsigned (*S)[2]  = Sw[w];

  float xE[NR], xO[NR];                       // even/odd chunk x-buffers

  auto load_chunk = [&](int k, float* dst) {  // lane = t-column
#pragma unroll
    for (int j = 0; j < NR; ++j) {
      const int gc = c0w - 6 + j;
      float v = 0.0f;
      if (gc >= 0 && gc < Cn)                 // zero pad; per-wave uniform
        v = x[xbase + (long)gc * Tn + k * TT + lane];
      dst[j] = v;
    }
  };
  auto conv_chunk = [&](const float* xs, float (*Dd)[DSTR]) {
#pragma unroll
    for (int c = 0; c < WC; ++c) {
      float acc = __fmul_rn(kw[0], xs[c]);    // ascending, no FMA
#pragma unroll
      for (int i = 1; i < KS; ++i)
        acc = __fadd_rn(acc, __fmul_rn(kw[i], xs[c + i]));
      Dd[c][lane] = __fsub_rn(xs[c + 6], acc);         // x - x_mean
    }
  };

  float mem = 0.0f, spkf = 0.0f;              // scan state, carried 1024 t

  auto scan_store = [&](int k, float (*Ds)[DSTR]) {
    if (lane < WC) {                          // lane = channel
      const float4* Dv = (const float4*)&Ds[lane][0];
      unsigned lo = 0u, hi = 0u;
      float dvA[16], dvB[16];                 // named groups, const idx only
      LOADG(dvA, 0)
      LOADG(dvB, 1)                           // lookahead one group
      SCAN16(dvA, 0,  lo)  LOADG(dvA, 2)
      SCAN16(dvB, 16, lo)  LOADG(dvB, 3)
      SCAN16(dvA, 32, hi)
      SCAN16(dvB, 48, hi)
      S[lane][0] = lo;  S[lane][1] = hi;
    }
    // broadcast + store (lane = t-column), fire & forget
    const long obase = xbase + (long)c0w * Tn + (long)k * TT + lane;
#pragma unroll
    for (int c = 0; c < WC; ++c) {
      const unsigned wlo = S[c][0], whi = S[c][1];     // LDS broadcast
      const unsigned ws  = (lane & 32) ? whi : wlo;
      out[obase + (long)c * Tn] = ((ws >> (lane & 31)) & 1u) ? 1.0f : 0.0f;
    }
  };

  // prologue: two chunks in flight, conv(0) ready
  load_chunk(0, xE);
  load_chunk(1, xO);
  conv_chunk(xE, D0);

  // steady state: loads(k+2) || conv(k+1) || scan+store(k)
  for (int k = 0; k < NCH; k += 2) {
    // even iter: loads k+2 -> xE (freed by conv(k) last iter), conv k+1 <- xO
    if (k + 2 < NCH) load_chunk(k + 2, xE);
    conv_chunk(xO, D1);
    scan_store(k, D0);
    // odd iter: loads k+3 -> xO, conv k+2 <- xE
    if (k + 3 < NCH) load_chunk(k + 3, xO);
    if (k + 2 < NCH) conv_chunk(xE, D0);
    scan_store(k + 1, D1);
  }
}

extern "C" void kernel_launch(void* const* d_in, const int* in_sizes, int n_in,
                              void* d_out, int out_size, void* d_ws, size_t ws_size,
                              hipStream_t stream) {
  const float* x  = (const float*)d_in[0];
  const float* w  = (const float*)d_in[1];
  float* out      = (float*)d_out;
  dim3 grid(Bn * Cn / (WC * WPB), 1, 1);      // 256 blocks x 256 threads
  snn_fused<<<grid, WPB * 64, 0, stream>>>(x, w, out);
}

// Round 7
// 131.651 us; speedup vs baseline: 1.0959x; 1.0112x over previous
//
#include <hip/hip_runtime.h>
#include <math.h>

// Problem constants
constexpr int Bn = 32;
constexpr int Cn = 512;
constexpr int Tn = 1024;
constexpr int KS = 13;

// Wave-pipeline tiling
constexpr int WC   = 8;             // channels owned per wave (r16: 16->8 => 2 waves/SIMD)
constexpr int TT   = 64;            // timesteps per chunk
constexpr int NCH  = Tn / TT;       // 16 chunks
constexpr int NR   = WC + KS - 1;   // 20 x-rows loaded per chunk
constexpr int DSTR = 68;            // Dw row stride: 272B rows, 16B-aligned (float4 reads);
                                    // scan lanes c<8 hit banks (4c)%32 -> conflict-free
constexpr int WPB  = 4;             // waves per block; 512 blocks -> 2 blocks/CU

// ---------------------------------------------------------------------------
// r16 = r15 with 2x TLP (pure parameter change; no new sync, no math change).
// r15 post-mortem: zero-barrier pipelines are correct and cheap (FETCH 38MB,
// conflicts 0) but at 1 wave/SIMD VALUBusy=36% -- each wave stalls 64% of
// cycles (scan dep chain ~12cyc/step, DS read-after-write at chunk start)
// with NOTHING else for the SIMD to issue. Pre-committed fork: dur>=40 ->
// add TLP. WC 16->8 gives 2048 waves = 2 blocks/CU = 2 waves/SIMD: each
// wave's bubbles are filled by the other pipeline's conv/load instrs.
// Known costs accepted: chip scan issue doubles (scan is 64 SSTEPs/chunk
// regardless of WC, now on 8 lanes), halo redundancy 1.75x->2.5x.
// Per-SIMD issue ~2x24K=48K cyc -> ~23us at 85% busy.
// Falsifier: dur>=35 && VALUBusy<45 -> stalls not latency-type; next lever
// is the balanced producer/consumer wave-pair split.
// Math (kw double-exp emulation, ascending no-FMA conv, compare-reuse scan)
// is bit-identical to the validated r9/r14/r15 kernels (all absmax 0.0).
// ---------------------------------------------------------------------------

// one scan step: reset uses PREVIOUS step's spike predicate (spkf), identical
// to computing (mem_old > 0.5 ? 0.5 : 0) -- validated r14/r15 (absmax 0.0).
#define SSTEP(DV, BP, W)                                                 \
  {                                                                      \
    const float rthr = spkf;                                             \
    float a_  = __fmul_rn(0.95f, mem);                                   \
    float s2_ = __fadd_rn(a_, (DV));                                     \
    mem = __fsub_rn(s2_, rthr);                                          \
    const bool sp_ = (mem > 0.5f);                                       \
    spkf = sp_ ? 0.5f : 0.0f;                                            \
    (W) |= sp_ ? (1u << (BP)) : 0u;                                      \
  }

// 16 scan steps from a 16-float register group into word W
#define SCAN16(DV, TB, W)                                                \
  _Pragma("unroll")                                                      \
  for (int j = 0; j < 16; ++j) {                                         \
    SSTEP(DV[j], (((TB) + j) & 31), W)                                   \
  }

// unpack one group of 4 float4s from Dv into a 16-float register array
#define LOADG(DV, G)                                                     \
  { float4 t0_ = Dv[4*(G)+0], t1_ = Dv[4*(G)+1],                         \
           t2_ = Dv[4*(G)+2], t3_ = Dv[4*(G)+3];                         \
    DV[0]=t0_.x;  DV[1]=t0_.y;  DV[2]=t0_.z;  DV[3]=t0_.w;               \
    DV[4]=t1_.x;  DV[5]=t1_.y;  DV[6]=t1_.z;  DV[7]=t1_.w;               \
    DV[8]=t2_.x;  DV[9]=t2_.y;  DV[10]=t2_.z; DV[11]=t2_.w;              \
    DV[12]=t3_.x; DV[13]=t3_.y; DV[14]=t3_.z; DV[15]=t3_.w; }

__global__ __launch_bounds__(256, 2)
void snn_fused(const float* __restrict__ x, const float* __restrict__ wp,
               float* __restrict__ out) {
  // per-wave private LDS: transpose dbuf + spike words (no cross-wave use)
  __shared__ __align__(16) float    Dw[WPB][2][WC][DSTR];  // 17.4 KB
  __shared__            unsigned    Sw[WPB][WC][2];        // 256 B

  const int tid  = threadIdx.x;
  const int w    = tid >> 6;                  // wave in block (0..3)
  const int lane = tid & 63;
  const int wid  = blockIdx.x * WPB + w;      // 0..2047
  const int b    = wid >> 6;                  // batch (0..31); 64 waves/batch
  const int c0w  = (wid & 63) * WC;           // first owned channel
  const long xbase = (long)b * Cn * Tn;

  // ---- Gaussian weights, numpy float32 bit-emulation (validated) ----
  float kw[KS];
  {
    float wv = wp[0];
    float wc = fminf(fmaxf(wv, 1.0f), 10.0f);     // clip(w, 1, 10)
    float sigma = __fadd_rn(5.5f, wc);
    float e[KS];
#pragma unroll
    for (int i = 0; i < KS; ++i) {
      float q = __fdiv_rn((float)(i - 6), sigma);
      float t = __fmul_rn(-0.5f, __fmul_rn(q, q));
      e[i] = (float)exp((double)t);
    }
    // numpy pairwise_sum order for n=13
    float s = __fadd_rn(
        __fadd_rn(__fadd_rn(e[0], e[1]), __fadd_rn(e[2], e[3])),
        __fadd_rn(__fadd_rn(e[4], e[5]), __fadd_rn(e[6], e[7])));
    s = __fadd_rn(s, e[8]);  s = __fadd_rn(s, e[9]);  s = __fadd_rn(s, e[10]);
    s = __fadd_rn(s, e[11]); s = __fadd_rn(s, e[12]);
#pragma unroll
    for (int i = 0; i < KS; ++i) kw[i] = __fdiv_rn(e[i], s);
  }

  float (*D0)[DSTR] = Dw[w][0];
  float (*D1)[DSTR] = Dw[w][1];
  unsigned (*S)[2]  = Sw[w];

  float xE[NR], xO[NR];                       // even/odd chunk x-buffers

  auto load_chunk = [&](int k, float* dst) {  // lane = t-column
#pragma unroll
    for (int j = 0; j < NR; ++j) {
      const int gc = c0w - 6 + j;
      float v = 0.0f;
      if (gc >= 0 && gc < Cn)                 // zero pad; per-wave uniform
        v = x[xbase + (long)gc * Tn + k * TT + lane];
      dst[j] = v;
    }
  };
  auto conv_chunk = [&](const float* xs, float (*Dd)[DSTR]) {
#pragma unroll
    for (int c = 0; c < WC; ++c) {
      float acc = __fmul_rn(kw[0], xs[c]);    // ascending, no FMA
#pragma unroll
      for (int i = 1; i < KS; ++i)
        acc = __fadd_rn(acc, __fmul_rn(kw[i], xs[c + i]));
      Dd[c][lane] = __fsub_rn(xs[c + 6], acc);         // x - x_mean
    }
  };

  float mem = 0.0f, spkf = 0.0f;              // scan state, carried 1024 t

  auto scan_store = [&](int k, float (*Ds)[DSTR]) {
    if (lane < WC) {                          // lane = channel
      const float4* Dv = (const float4*)&Ds[lane][0];
      unsigned lo = 0u, hi = 0u;
      float dvA[16], dvB[16];                 // named groups, const idx only
      LOADG(dvA, 0)
      LOADG(dvB, 1)                           // lookahead one group
      SCAN16(dvA, 0,  lo)  LOADG(dvA, 2)
      SCAN16(dvB, 16, lo)  LOADG(dvB, 3)
      SCAN16(dvA, 32, hi)
      SCAN16(dvB, 48, hi)
      S[lane][0] = lo;  S[lane][1] = hi;
    }
    // broadcast + store (lane = t-column), fire & forget
    const long obase = xbase + (long)c0w * Tn + (long)k * TT + lane;
#pragma unroll
    for (int c = 0; c < WC; ++c) {
      const unsigned wlo = S[c][0], whi = S[c][1];     // LDS broadcast
      const unsigned ws  = (lane & 32) ? whi : wlo;
      out[obase + (long)c * Tn] = ((ws >> (lane & 31)) & 1u) ? 1.0f : 0.0f;
    }
  };

  // prologue: two chunks in flight, conv(0) ready
  load_chunk(0, xE);
  load_chunk(1, xO);
  conv_chunk(xE, D0);

  // steady state: loads(k+2) || conv(k+1) || scan+store(k)
  for (int k = 0; k < NCH; k += 2) {
    // even iter: loads k+2 -> xE (freed by conv(k) last iter), conv k+1 <- xO
    if (k + 2 < NCH) load_chunk(k + 2, xE);
    conv_chunk(xO, D1);
    scan_store(k, D0);
    // odd iter: loads k+3 -> xO, conv k+2 <- xE
    if (k + 3 < NCH) load_chunk(k + 3, xO);
    if (k + 2 < NCH) conv_chunk(xE, D0);
    scan_store(k + 1, D1);
  }
}

extern "C" void kernel_launch(void* const* d_in, const int* in_sizes, int n_in,
                              void* d_out, int out_size, void* d_ws, size_t ws_size,
                              hipStream_t stream) {
  const float* x  = (const float*)d_in[0];
  const float* w  = (const float*)d_in[1];
  float* out      = (float*)d_out;
  dim3 grid(Bn * Cn / (WC * WPB), 1, 1);      // 512 blocks x 256 threads
  snn_fused<<<grid, WPB * 64, 0, stream>>>(x, w, out);
}